// Round 15
// baseline (241.713 us; speedup 1.0000x reference)
//
#include <hip/hip_runtime.h>

#define LQ     21760
#define NBATCH 2
#define MROWS  (NBATCH * LQ)   // 43520 rows for all GEMMs
#define QB16   (MROWS / 16)    // 2720 q-blocks per head (16 tasks/block)

typedef __attribute__((ext_vector_type(8))) short bf16x8;
typedef __attribute__((ext_vector_type(4))) float f32x4;

__device__ __forceinline__ unsigned short f2bf(float f) {
    unsigned u = __builtin_bit_cast(unsigned, f);
    return (unsigned short)((u + 0x7fffu + ((u >> 16) & 1u)) >> 16);  // RNE
}
__device__ __forceinline__ float bf2f(unsigned short h) {
    return __builtin_bit_cast(float, (unsigned)h << 16);
}
__device__ __forceinline__ float f16lo(unsigned u) {
    return (float)__builtin_bit_cast(_Float16, (unsigned short)(u & 0xffffu));
}
__device__ __forceinline__ float f16hi(unsigned u) {
    return (float)__builtin_bit_cast(_Float16, (unsigned short)(u >> 16));
}

// DPP row-rotate (within 16-lane rows) on the VALU pipe — no DS traffic.
template <int CTRL>
__device__ __forceinline__ float fdpp(float v) {
    int r = __builtin_amdgcn_update_dpp(
        0, __builtin_bit_cast(int, v), CTRL, 0xf, 0xf, false);
    return __builtin_bit_cast(float, r);
}

// ---------------------------------------------------------------------------
// All four weight matrices: W[256][N] fp32 -> Wt[N][256] bf16, one launch.
// ---------------------------------------------------------------------------
__global__ __launch_bounds__(256) void cvt_wall(
    const float* __restrict__ Wv, const float* __restrict__ Wo,
    const float* __restrict__ Wa, const float* __restrict__ Wu,
    short* __restrict__ Wtv, short* __restrict__ Wcat, short* __restrict__ Wtu)
{
    int idx = blockIdx.x * 256 + threadIdx.x;
    if (idx < 65536) {
        int nn = idx >> 8, k = idx & 255;
        Wtv[idx] = (short)f2bf(Wv[k * 256 + nn]);
    } else if (idx < 131072) {
        int j = idx - 65536; int nn = j >> 8, k = j & 255;
        Wcat[j] = (short)f2bf(Wo[k * 256 + nn]);
    } else if (idx < 163840) {
        int j = idx - 131072; int nn = j >> 8, k = j & 255;
        Wcat[65536 + j] = (short)f2bf(Wa[k * 128 + nn]);
    } else if (idx < 229376) {
        int j = idx - 163840; int nn = j >> 8, k = j & 255;
        Wtu[j] = (short)f2bf(Wu[k * 256 + nn]);
    }
}

// ---------------------------------------------------------------------------
// MFMA GEMM: C[M x N] = A[M x 256] * Bt[N x 256]^T + bias
// Tile 128x128, 4 waves (2x2), BK=64, K=256 fixed.
// AF32=1: A fp32, converted to bf16 during LDS staging (v_cvt_pk_bf16_f32).
// OMODE: 0 = f32 out, 1 = bf16 out, 2 = f16 out,
//        3 = split off/attn (N=384) in HEAD-MAJOR layouts,
//        4 = f16 head-major value layout (head, pixel, 32ch).
// ---------------------------------------------------------------------------
template <int AF32, int OMODE>
__global__ __launch_bounds__(256) void gemm_mfma(
    const void* __restrict__ Aptr,
    const short* __restrict__ Bt,
    const float* __restrict__ bias,
    const float* __restrict__ bias2,
    void* __restrict__ Cout,
    void* __restrict__ Cout2,
    int N)
{
    __shared__ short Al[128 * 64];
    __shared__ short Bl[128 * 64];

    const int tid  = threadIdx.x;
    const int lane = tid & 63, wid = tid >> 6;
    const int wr = wid >> 1, wc = wid & 1;
    const int bx = blockIdx.x, by = blockIdx.y;

    const long arow0 = (long)by * 128;
    const int  brow0 = bx * 128;

    const short* Abf = (const short*)Aptr;
    const float* Af  = (const float*)Aptr;

    f32x4 acc[4][4];
#pragma unroll
    for (int i = 0; i < 4; ++i)
#pragma unroll
        for (int j = 0; j < 4; ++j) acc[i][j] = (f32x4)0.f;

    bf16x8 ra[4], rb[4];
    float4 raf[4][2];

#pragma unroll
    for (int i = 0; i < 4; ++i) {
        int id = tid + i * 256, r = id >> 3, c = id & 7;
        if (AF32) {
            raf[i][0] = *(const float4*)(Af + (arow0 + r) * 256 + c * 8);
            raf[i][1] = *(const float4*)(Af + (arow0 + r) * 256 + c * 8 + 4);
        } else {
            ra[i] = *(const bf16x8*)(Abf + (arow0 + r) * 256 + c * 8);
        }
        rb[i] = *(const bf16x8*)(Bt + (long)(brow0 + r) * 256 + c * 8);
    }

    for (int step = 0; step < 4; ++step) {
#pragma unroll
        for (int i = 0; i < 4; ++i) {
            int id = tid + i * 256, r = id >> 3, c = id & 7;
            bf16x8 av;
            if (AF32) {
                unsigned q0, q1, q2, q3;
                asm("v_cvt_pk_bf16_f32 %0, %1, %2" : "=v"(q0) : "v"(raf[i][0].x), "v"(raf[i][0].y));
                asm("v_cvt_pk_bf16_f32 %0, %1, %2" : "=v"(q1) : "v"(raf[i][0].z), "v"(raf[i][0].w));
                asm("v_cvt_pk_bf16_f32 %0, %1, %2" : "=v"(q2) : "v"(raf[i][1].x), "v"(raf[i][1].y));
                asm("v_cvt_pk_bf16_f32 %0, %1, %2" : "=v"(q3) : "v"(raf[i][1].z), "v"(raf[i][1].w));
                uint4 u = make_uint4(q0, q1, q2, q3);
                av = __builtin_bit_cast(bf16x8, u);
            } else {
                av = ra[i];
            }
            *(bf16x8*)(Al + r * 64 + ((c ^ (r & 7)) * 8)) = av;
            *(bf16x8*)(Bl + r * 64 + ((c ^ (r & 7)) * 8)) = rb[i];
        }
        __syncthreads();
        if (step < 3) {
            const int k0 = (step + 1) * 64;
#pragma unroll
            for (int i = 0; i < 4; ++i) {
                int id = tid + i * 256, r = id >> 3, c = id & 7;
                if (AF32) {
                    raf[i][0] = *(const float4*)(Af + (arow0 + r) * 256 + k0 + c * 8);
                    raf[i][1] = *(const float4*)(Af + (arow0 + r) * 256 + k0 + c * 8 + 4);
                } else {
                    ra[i] = *(const bf16x8*)(Abf + (arow0 + r) * 256 + k0 + c * 8);
                }
                rb[i] = *(const bf16x8*)(Bt + (long)(brow0 + r) * 256 + k0 + c * 8);
            }
        }
#pragma unroll
        for (int kk = 0; kk < 2; ++kk) {
            const int g = lane >> 4;
            const int chunk = kk * 4 + g;
            bf16x8 af[4], bg[4];
#pragma unroll
            for (int mi = 0; mi < 4; ++mi) {
                int r = wr * 64 + mi * 16 + (lane & 15);
                af[mi] = *(const bf16x8*)(Al + r * 64 + ((chunk ^ (r & 7)) * 8));
            }
#pragma unroll
            for (int ni = 0; ni < 4; ++ni) {
                int r = wc * 64 + ni * 16 + (lane & 15);
                bg[ni] = *(const bf16x8*)(Bl + r * 64 + ((chunk ^ (r & 7)) * 8));
            }
#pragma unroll
            for (int mi = 0; mi < 4; ++mi)
#pragma unroll
                for (int ni = 0; ni < 4; ++ni)
                    acc[mi][ni] = __builtin_amdgcn_mfma_f32_16x16x32_bf16(
                        af[mi], bg[ni], acc[mi][ni], 0, 0, 0);
        }
        __syncthreads();
    }

#pragma unroll
    for (int mi = 0; mi < 4; ++mi) {
#pragma unroll
        for (int ni = 0; ni < 4; ++ni) {
            const int  col = bx * 128 + wc * 64 + ni * 16 + (lane & 15);
            const long row = (long)by * 128 + wr * 64 + mi * 16 + ((lane >> 4) * 4);
            float b;
            if (OMODE == 3) b = (col < 256) ? bias[col] : bias2[col - 256];
            else            b = bias[col];
#pragma unroll
            for (int q = 0; q < 4; ++q) {
                float v = acc[mi][ni][q] + b;
                if (OMODE == 0) {
                    ((float*)Cout)[(row + q) * N + col] = v;
                } else if (OMODE == 1) {
                    ((unsigned short*)Cout)[(row + q) * N + col] = f2bf(v);
                } else if (OMODE == 2) {
                    ((unsigned short*)Cout)[(row + q) * N + col] =
                        __builtin_bit_cast(unsigned short, (_Float16)v);
                } else if (OMODE == 4) {
                    const int mh = col >> 5, ch = col & 31;
                    ((unsigned short*)Cout)[((size_t)mh * MROWS + (row + q)) * 32 + ch] =
                        __builtin_bit_cast(unsigned short, (_Float16)v);
                } else {
                    if (col < 256) {
                        const int mh = col >> 5, ch = col & 31;
                        ((unsigned short*)Cout)[((size_t)mh * MROWS + (row + q)) * 32 + ch] = f2bf(v);
                    } else {
                        const int cc = col - 256;
                        const int mh = cc >> 4, k = cc & 15;
                        ((unsigned short*)Cout2)[((size_t)mh * MROWS + (row + q)) * 16 + k] = f2bf(v);
                    }
                }
            }
        }
    }
}

// ---------------------------------------------------------------------------
// Fused softmax + sampling; value f16 HEAD-MAJOR (head, pixel, 32ch).
// FOUR tasks per wave. Reduce: DPP ror:8 (slot parity) + ror:4 (L/R fold)
// leave only cross-row sums -> part LDS shrinks to [16] reps (10KB total
// with meta = 14.25KB) -> 8 blocks/CU occupancy (was 6 at 24.6KB).
// ---------------------------------------------------------------------------
__device__ __forceinline__ void fma8(float (&a)[8], uint4 v, float w) {
    a[0] = fmaf(f16lo(v.x), w, a[0]);
    a[1] = fmaf(f16hi(v.x), w, a[1]);
    a[2] = fmaf(f16lo(v.y), w, a[2]);
    a[3] = fmaf(f16hi(v.y), w, a[3]);
    a[4] = fmaf(f16lo(v.z), w, a[4]);
    a[5] = fmaf(f16hi(v.z), w, a[5]);
    a[6] = fmaf(f16lo(v.w), w, a[6]);
    a[7] = fmaf(f16hi(v.w), w, a[7]);
}

__global__ __launch_bounds__(256, 8) void ms_sample_f16v(
    const unsigned short* __restrict__ valuef16, // (8, 43520, 32) f16 head-major
    const unsigned short* __restrict__ offbf,    // (8, 43520, 32) bf16 head-major
    const unsigned short* __restrict__ attnbf,   // (8, 43520, 16) bf16 head-major
    const float* __restrict__ refpts,            // (43520, 4, 2)
    unsigned short* __restrict__ accbf)          // (43520, 256) bf16
{
    __shared__ uint2 meta_lds[4][4][32];     // 4 KB
    __shared__ float part[4][4][16][10];     // 10.25 KB padded (40B stride)

    const int lane = threadIdx.x & 63;
    const int wid  = threadIdx.x >> 6;
    const int b    = blockIdx.x;
    const int m    = b / QB16;                  // head-major grid
    const int qblk = b - m * QB16;
    const int qn0w = qblk * 16 + 4 * wid;       // first qn of this wave

    // ---------------- producer: lane = p + 16*tq ----------------
    const int p   = lane & 15;
    const int tq  = lane >> 4;                  // task 0..3
    const int lvl = p >> 2;
    const int pt  = p & 3;
    const int qnl = qn0w + tq;
    const int nb  = (qnl >= LQ) ? 1 : 0;

    const size_t hq = (size_t)m * MROWS + qnl;  // head-major row index

    float lg = bf2f(attnbf[hq * 16 + p]);

    // softmax over the 16 p-lanes of this row (one row = one task)
    float mx = lg;
    mx = fmaxf(mx, fdpp<0x128>(mx));   // ror:8
    mx = fmaxf(mx, fdpp<0x124>(mx));   // ror:4
    mx = fmaxf(mx, fdpp<0x122>(mx));   // ror:2
    mx = fmaxf(mx, fdpp<0x121>(mx));   // ror:1
    float e = __expf(lg - mx);
    float s = e;
    s += fdpp<0x128>(s);
    s += fdpp<0x124>(s);
    s += fdpp<0x122>(s);
    s += fdpp<0x121>(s);
    const float aw = e * (1.0f / s);

    const int W  = 128 >> lvl;
    const int st = (lvl == 0) ? 0 : (lvl == 1) ? 16384
                 : (lvl == 2) ? 20480 : 21504;
    const float fW = (float)W;

    const float2 rxy = *(const float2*)&refpts[(size_t)qnl * 8 + lvl * 2];
    unsigned oo = *(const unsigned*)(offbf + hq * 32 + lvl * 8 + pt * 2);
    const float ox = bf2f((unsigned short)(oo & 0xffff));
    const float oy = bf2f((unsigned short)(oo >> 16));

    const float x = fmaf(rxy.x, fW, ox) - 0.5f;
    const float y = fmaf(rxy.y, fW, oy) - 0.5f;
    const float x0f = floorf(x), y0f = floorf(y);
    const float fx = x - x0f, fy = y - y0f;
    const int x0i = (int)x0f;
    const int y0i = (int)y0f;

    // y-row weights (both rows in one lane)
    const bool y0ok = (y0i >= 0) & (y0i <= W - 1);
    const bool y1ok = (y0i + 1 >= 0) & (y0i + 1 <= W - 1);
    const float awwy0 = y0ok ? aw * (1.0f - fy) : 0.0f;
    const float awwy1 = y1ok ? aw * fy : 0.0f;
    const int yc0 = min(max(y0i, 0), W - 1);
    const int yc1 = min(max(y0i + 1, 0), W - 1);

    // x-pair (shared across both y-rows)
    const bool x0ok = (x0i >= 0) & (x0i <= W - 1);
    const bool x1ok = (x0i + 1 >= 0) & (x0i + 1 <= W - 1);
    const float wx0 = x0ok ? (1.0f - fx) : 0.0f;
    const float wx1 = x1ok ? fx : 0.0f;
    const int bxp = min(max(x0i, 0), W - 2);
    const bool bis = (x0i == bxp);
    const float wxl = bis ? wx0 : wx1;
    const float wxr = bis ? wx1 : wx0;

    const int base0 = nb * 21760 + st + bxp;
    const int addr0 = base0 + yc0 * W;
    const int addr1 = base0 + yc1 * W;

    const unsigned wp0 =
        (unsigned)__builtin_bit_cast(unsigned short, (_Float16)(awwy0 * wxl)) |
        ((unsigned)__builtin_bit_cast(unsigned short, (_Float16)(awwy0 * wxr)) << 16);
    const unsigned wp1 =
        (unsigned)__builtin_bit_cast(unsigned short, (_Float16)(awwy1 * wxl)) |
        ((unsigned)__builtin_bit_cast(unsigned short, (_Float16)(awwy1 * wxr)) << 16);

    meta_lds[wid][tq][p * 2 + 0] = make_uint2((unsigned)addr0, wp0);
    meta_lds[wid][tq][p * 2 + 1] = make_uint2((unsigned)addr1, wp1);

    asm volatile("s_waitcnt lgkmcnt(0)" ::: "memory");
    __builtin_amdgcn_sched_barrier(0);

    // ---------------- consumer: lane = cg + 8*slot ----------------
    const int cg   = lane & 7;
    const int slot = lane >> 3;
    const char* vbh = (const char*)(valuef16 + (size_t)m * MROWS * 32);
    const unsigned mc = (unsigned)(cg * 16);
    const int wsh = (cg >> 2) << 4;     // 0: L-pixel weight, 16: R-pixel

    float a0[8] = {}, a1[8] = {}, a2[8] = {}, a3[8] = {};

    auto do_task = [&](int t, float (&a)[8]) {
        uint2 mt[4];
#pragma unroll
        for (int it = 0; it < 4; ++it)
            mt[it] = meta_lds[wid][t][it * 8 + slot];
        uint4 vv[4];
#pragma unroll
        for (int it = 0; it < 4; ++it)
            vv[it] = *(const uint4*)(vbh + (((size_t)mt[it].x) << 6) + mc);
#pragma unroll
        for (int it = 0; it < 4; ++it) {
            const float w = (float)__builtin_bit_cast(
                _Float16, (unsigned short)((mt[it].y >> wsh) & 0xffffu));
            fma8(a, vv[it], w);
        }
    };
    do_task(0, a0);
    do_task(1, a1);
    do_task(2, a2);
    do_task(3, a3);

    // fold slot parity (lane^8) then L/R half (lane^4) on the VALU pipe;
    // after both, all 16 lanes of a row hold the row's partial sum.
#pragma unroll
    for (int jj = 0; jj < 8; ++jj) {
        a0[jj] += fdpp<0x128>(a0[jj]);
        a1[jj] += fdpp<0x128>(a1[jj]);
        a2[jj] += fdpp<0x128>(a2[jj]);
        a3[jj] += fdpp<0x128>(a3[jj]);
    }
#pragma unroll
    for (int jj = 0; jj < 8; ++jj) {
        a0[jj] += fdpp<0x124>(a0[jj]);
        a1[jj] += fdpp<0x124>(a1[jj]);
        a2[jj] += fdpp<0x124>(a2[jj]);
        a3[jj] += fdpp<0x124>(a3[jj]);
    }

    // representative lanes (lane&12 == 0): idx = row*4 + octet
    if ((lane & 12) == 0) {
        const int idx = (lane >> 4) * 4 + (lane & 3);
        float* pp0 = &part[wid][0][idx][0];
        float* pp1 = &part[wid][1][idx][0];
        float* pp2 = &part[wid][2][idx][0];
        float* pp3 = &part[wid][3][idx][0];
        *(float2*)&pp0[0] = make_float2(a0[0], a0[1]);
        *(float2*)&pp0[2] = make_float2(a0[2], a0[3]);
        *(float2*)&pp0[4] = make_float2(a0[4], a0[5]);
        *(float2*)&pp0[6] = make_float2(a0[6], a0[7]);
        *(float2*)&pp1[0] = make_float2(a1[0], a1[1]);
        *(float2*)&pp1[2] = make_float2(a1[2], a1[3]);
        *(float2*)&pp1[4] = make_float2(a1[4], a1[5]);
        *(float2*)&pp1[6] = make_float2(a1[6], a1[7]);
        *(float2*)&pp2[0] = make_float2(a2[0], a2[1]);
        *(float2*)&pp2[2] = make_float2(a2[2], a2[3]);
        *(float2*)&pp2[4] = make_float2(a2[4], a2[5]);
        *(float2*)&pp2[6] = make_float2(a2[6], a2[7]);
        *(float2*)&pp3[0] = make_float2(a3[0], a3[1]);
        *(float2*)&pp3[2] = make_float2(a3[2], a3[3]);
        *(float2*)&pp3[4] = make_float2(a3[4], a3[5]);
        *(float2*)&pp3[6] = make_float2(a3[6], a3[7]);
    }
    asm volatile("s_waitcnt lgkmcnt(0)" ::: "memory");
    __builtin_amdgcn_sched_barrier(0);

    // 64 lanes write all 4 tasks: lanes 0-31 -> tasks {0,1}, 32-63 -> {2,3};
    // sum the 4 row-partials from LDS.
#pragma unroll
    for (int tt = 0; tt < 2; ++tt) {
        const int t  = (lane >> 5) * 2 + tt;
        const int ch = lane & 31;
        const int o  = ch >> 3, k = ch & 7;
        float sum = 0.f;
#pragma unroll
        for (int row = 0; row < 4; ++row)
            sum += part[wid][t][row * 4 + o][k];
        accbf[(size_t)(qn0w + t) * 256 + m * 32 + ch] = f2bf(sum);
    }
}

// ---------------------------------------------------------------------------
// fp32 fallback kernels (used only if workspace is too small)
// ---------------------------------------------------------------------------
__global__ __launch_bounds__(256) void gemm_k256(
    const float* __restrict__ A, const float* __restrict__ B,
    const float* __restrict__ bias, float* __restrict__ C,
    int M, int N)
{
    __shared__ float As[16][68];
    __shared__ float Bs[16][68];

    const int tid = threadIdx.x;
    const int tx = tid & 15, ty = tid >> 4;
    const int bx = blockIdx.x, by = blockIdx.y;

    const int arow = tid >> 2;
    const int ak   = (tid & 3) << 2;
    const int bk   = tid >> 4;
    const int bcol = (tid & 15) << 2;

    const float* Ag = A + (long)(by * 64 + arow) * 256 + ak;
    const float* Bg = B + (long)bk * N + bx * 64 + bcol;

    float acc[4][4] = {};

    for (int k0 = 0; k0 < 256; k0 += 16) {
        float4 av = *(const float4*)(Ag + k0);
        float4 bv = *(const float4*)(Bg + (long)k0 * N);
        As[ak + 0][arow] = av.x;
        As[ak + 1][arow] = av.y;
        As[ak + 2][arow] = av.z;
        As[ak + 3][arow] = av.w;
        *(float4*)&Bs[bk][bcol] = bv;
        __syncthreads();
#pragma unroll
        for (int k = 0; k < 16; ++k) {
            float4 a4 = *(const float4*)&As[k][ty * 4];
            float4 b4 = *(const float4*)&Bs[k][tx * 4];
            float a[4] = {a4.x, a4.y, a4.z, a4.w};
            float bb[4] = {b4.x, b4.y, b4.z, b4.w};
#pragma unroll
            for (int i = 0; i < 4; ++i)
#pragma unroll
                for (int j = 0; j < 4; ++j)
                    acc[i][j] = fmaf(a[i], bb[j], acc[i][j]);
        }
        __syncthreads();
    }

    float4 b4 = *(const float4*)&bias[bx * 64 + tx * 4];
#pragma unroll
    for (int i = 0; i < 4; ++i) {
        float4 o;
        o.x = acc[i][0] + b4.x;
        o.y = acc[i][1] + b4.y;
        o.z = acc[i][2] + b4.z;
        o.w = acc[i][3] + b4.w;
        *(float4*)&C[(long)(by * 64 + ty * 4 + i) * N + bx * 64 + tx * 4] = o;
    }
}

__global__ __launch_bounds__(256) void ms_sample_f32(
    const float* __restrict__ value,
    const float* __restrict__ offraw,
    const float* __restrict__ attnraw,
    const float* __restrict__ refpts,
    float* __restrict__ acc_out)
{
    const int lane = threadIdx.x & 63;
    const int wid  = threadIdx.x >> 6;
    const long t   = (long)blockIdx.x * 4 + wid;

    const int  m  = (int)(t & 7);
    const long qn = t >> 3;

    const int p   = lane >> 2;
    const int c   = lane & 3;
    const int cx  = c & 1, cy = c >> 1;
    const int lvl = p >> 2;
    const int pt  = p & 3;

    float lg = attnraw[qn * 128 + m * 16 + p];
    float mx = lg;
    mx = fmaxf(mx, __shfl_xor(mx, 4));
    mx = fmaxf(mx, __shfl_xor(mx, 8));
    mx = fmaxf(mx, __shfl_xor(mx, 16));
    mx = fmaxf(mx, __shfl_xor(mx, 32));
    float e = __expf(lg - mx);
    float s = e;
    s += __shfl_xor(s, 4);
    s += __shfl_xor(s, 8);
    s += __shfl_xor(s, 16);
    s += __shfl_xor(s, 32);
    const float aw = e * (1.0f / s);

    const int W  = 128 >> lvl;
    const int st = (lvl == 0) ? 0 : (lvl == 1) ? 16384
                 : (lvl == 2) ? 20480 : 21504;
    const float fW = (float)W;

    const float2 rxy = *(const float2*)&refpts[qn * 8 + lvl * 2];
    float2 o2 = *(const float2*)(offraw + qn * 256 + m * 32 + lvl * 8 + pt * 2);

    const float x = fmaf(rxy.x, fW, o2.x) - 0.5f;
    const float y = fmaf(rxy.y, fW, o2.y) - 0.5f;
    const float x0f = floorf(x), y0f = floorf(y);
    const float fx = x - x0f, fy = y - y0f;
    const int xi = (int)x0f + cx;
    const int yi = (int)y0f + cy;
    const float wx = cx ? fx : (1.0f - fx);
    const float wy = cy ? fy : (1.0f - fy);
    const bool ok = (xi >= 0) & (xi <= W - 1) & (yi >= 0) & (yi <= W - 1);
    const float wt = ok ? aw * wx * wy : 0.0f;
    const int xc = min(max(xi, 0), W - 1);
    const int yc = min(max(yi, 0), W - 1);
    const int addr = st + yc * W + xc;

    const int cg   = lane & 7;
    const int slot = lane >> 3;

    const long nn = qn / LQ;
    const float4* v4 = (const float4*)(value + (nn * (long)LQ) * 256 + m * 32);

    float4 acc = make_float4(0.f, 0.f, 0.f, 0.f);
#pragma unroll
    for (int it = 0; it < 8; ++it) {
        const int src = 8 * it + slot;
        const int   a = __shfl(addr, src);
        const float w = __shfl(wt, src);
        const float4 v = v4[(long)a * 64 + cg];
        acc.x = fmaf(w, v.x, acc.x);
        acc.y = fmaf(w, v.y, acc.y);
        acc.z = fmaf(w, v.z, acc.z);
        acc.w = fmaf(w, v.w, acc.w);
    }

#pragma unroll
    for (int mask = 8; mask <= 32; mask <<= 1) {
        acc.x += __shfl_xor(acc.x, mask);
        acc.y += __shfl_xor(acc.y, mask);
        acc.z += __shfl_xor(acc.z, mask);
        acc.w += __shfl_xor(acc.w, mask);
    }

    if (lane < 8)
        *(float4*)(acc_out + qn * 256 + m * 32 + cg * 4) = acc;
}

__global__ __launch_bounds__(256) void outproj_inplace(
    float* __restrict__ io, const float* __restrict__ W,
    const float* __restrict__ bias)
{
    __shared__ float As[32][260];
    __shared__ float Bs[16][260];

    const int tid = threadIdx.x;
    const long rbase = (long)blockIdx.x * 32;

#pragma unroll
    for (int i = 0; i < 8; ++i) {
        int f4 = i * 256 + tid;
        int r  = f4 >> 6;
        int c4 = (f4 & 63) << 2;
        float4 v = *(const float4*)&io[(rbase + r) * 256 + c4];
        *(float4*)&As[r][c4] = v;
    }
    __syncthreads();

    const int tx = tid & 15, ty = tid >> 4;
    float acc[2][16] = {};

    for (int k0 = 0; k0 < 256; k0 += 16) {
#pragma unroll
        for (int i = 0; i < 4; ++i) {
            int f4 = i * 256 + tid;
            int kr = f4 >> 6;
            int c4 = (f4 & 63) << 2;
            float4 v = *(const float4*)&W[(long)(k0 + kr) * 256 + c4];
            *(float4*)&Bs[kr][c4] = v;
        }
        __syncthreads();
#pragma unroll
        for (int k = 0; k < 16; ++k) {
            float a0 = As[ty * 2 + 0][k0 + k];
            float a1 = As[ty * 2 + 1][k0 + k];
#pragma unroll
            for (int jj = 0; jj < 4; ++jj) {
                float4 b = *(const float4*)&Bs[k][tx * 4 + jj * 64];
                acc[0][jj * 4 + 0] = fmaf(a0, b.x, acc[0][jj * 4 + 0]);
                acc[0][jj * 4 + 1] = fmaf(a0, b.y, acc[0][jj * 4 + 1]);
                acc[0][jj * 4 + 2] = fmaf(a0, b.z, acc[0][jj * 4 + 2]);
                acc[0][jj * 4 + 3] = fmaf(a0, b.w, acc[0][jj * 4 + 3]);
                acc[1][jj * 4 + 0] = fmaf(a1, b.x, acc[1][jj * 4 + 0]);
                acc[1][jj * 4 + 1] = fmaf(a1, b.y, acc[1][jj * 4 + 1]);
                acc[1][jj * 4 + 2] = fmaf(a1, b.z, acc[1][jj * 4 + 2]);
                acc[1][jj * 4 + 3] = fmaf(a1, b.w, acc[1][jj * 4 + 3]);
            }
        }
        __syncthreads();
    }

#pragma unroll
    for (int i = 0; i < 2; ++i)
#pragma unroll
        for (int jj = 0; jj < 4; ++jj) {
            float4 b = *(const float4*)&bias[tx * 4 + jj * 64];
            float4 o;
            o.x = acc[i][jj * 4 + 0] + b.x;
            o.y = acc[i][jj * 4 + 1] + b.y;
            o.z = acc[i][jj * 4 + 2] + b.z;
            o.w = acc[i][jj * 4 + 3] + b.w;
            *(float4*)&io[(rbase + ty * 2 + i) * 256 + tx * 4 + jj * 64] = o;
        }
}

// ---------------------------------------------------------------------------
extern "C" void kernel_launch(void* const* d_in, const int* in_sizes, int n_in,
                              void* d_out, int out_size, void* d_ws, size_t ws_size,
                              hipStream_t stream)
{
    const float* query         = (const float*)d_in[0];
    const float* refpts        = (const float*)d_in[1];
    const float* input_flatten = (const float*)d_in[2];
    const float* W_off         = (const float*)d_in[3];
    const float* b_off         = (const float*)d_in[4];
    const float* W_attn        = (const float*)d_in[5];
    const float* b_attn        = (const float*)d_in[6];
    const float* W_val         = (const float*)d_in[7];
    const float* b_val         = (const float*)d_in[8];
    const float* W_out         = (const float*)d_in[9];
    const float* b_out         = (const float*)d_in[10];
    float* out = (float*)d_out;

    dim3 blk(256);

    const size_t NEED_BF = 78446592ULL;
    if (ws_size >= NEED_BF) {
        // -------- bf16/f16 MFMA path --------
        char* w = (char*)d_ws;
        unsigned short* valuef16 = (unsigned short*)w;               // 22,282,240
        unsigned short* offbf    = (unsigned short*)(w + 22282240);  // 22,282,240
        unsigned short* attnbf   = (unsigned short*)(w + 44564480);  // 11,141,120
        unsigned short* accbf    = (unsigned short*)(w + 55705600);  // 22,282,240
        short*          Wtv      = (short*)(w + 77987840);           // 131,072
        short*          Wcat     = (short*)(w + 78118912);           // 196,608
        short*          Wtu      = (short*)(w + 78315520);           // 131,072

        cvt_wall<<<dim3(896), blk, 0, stream>>>(
            W_val, W_off, W_attn, W_out, Wtv, Wcat, Wtu);

        // value in f16 head-major (head, pixel, 32ch)
        gemm_mfma<1, 4><<<dim3(2, MROWS / 128), blk, 0, stream>>>(
            input_flatten, Wtv, b_val, nullptr, valuef16, nullptr, 256);
        // off/attn in head-major layouts
        gemm_mfma<1, 3><<<dim3(3, MROWS / 128), blk, 0, stream>>>(
            query, Wcat, b_off, b_attn, offbf, attnbf, 384);

        // head-major grid, 16 tasks/block (4 tasks per wave)
        ms_sample_f16v<<<dim3(QB16 * 8), blk, 0, stream>>>(
            valuef16, offbf, attnbf, refpts, accbf);

        gemm_mfma<0, 0><<<dim3(2, MROWS / 128), blk, 0, stream>>>(
            accbf, Wtu, b_out, nullptr, out, nullptr, 256);
    } else {
        // -------- fp32 fallback path --------
        float* ws = (float*)d_ws;
        float* value   = ws;
        float* offraw  = value  + (long)MROWS * 256;
        float* attnraw = offraw + (long)MROWS * 256;
        float* accbuf  = attnraw + (long)MROWS * 128;

        const size_t need_with_acc =
            ((size_t)MROWS * 256 * 3 + (size_t)MROWS * 128) * sizeof(float);
        const bool has_acc = ws_size >= need_with_acc;

        gemm_k256<<<dim3(4, MROWS / 64), blk, 0, stream>>>(input_flatten, W_val, b_val, value, MROWS, 256);
        gemm_k256<<<dim3(4, MROWS / 64), blk, 0, stream>>>(query, W_off, b_off, offraw, MROWS, 256);
        gemm_k256<<<dim3(2, MROWS / 64), blk, 0, stream>>>(query, W_attn, b_attn, attnraw, MROWS, 128);

        float* accp = has_acc ? accbuf : out;
        ms_sample_f32<<<dim3((NBATCH * LQ * 8) / 4), blk, 0, stream>>>(
            value, offraw, attnraw, refpts, accp);

        if (has_acc)
            gemm_k256<<<dim3(4, MROWS / 64), blk, 0, stream>>>(accbuf, W_out, b_out, out, MROWS, 256);
        else
            outproj_inplace<<<dim3(MROWS / 32), blk, 0, stream>>>(out, W_out, b_out);
    }
}

// Round 16
// 151.166 us; speedup vs baseline: 1.5990x; 1.5990x over previous
//
#include <hip/hip_runtime.h>

#define LQ     21760
#define NBATCH 2
#define MROWS  (NBATCH * LQ)   // 43520 rows for all GEMMs
#define QB16   (MROWS / 16)    // 2720 q-blocks per head (16 tasks/block)

typedef __attribute__((ext_vector_type(8))) short bf16x8;
typedef __attribute__((ext_vector_type(4))) float f32x4;

__device__ __forceinline__ unsigned short f2bf(float f) {
    unsigned u = __builtin_bit_cast(unsigned, f);
    return (unsigned short)((u + 0x7fffu + ((u >> 16) & 1u)) >> 16);  // RNE
}
__device__ __forceinline__ float bf2f(unsigned short h) {
    return __builtin_bit_cast(float, (unsigned)h << 16);
}
__device__ __forceinline__ float f16lo(unsigned u) {
    return (float)__builtin_bit_cast(_Float16, (unsigned short)(u & 0xffffu));
}
__device__ __forceinline__ float f16hi(unsigned u) {
    return (float)__builtin_bit_cast(_Float16, (unsigned short)(u >> 16));
}

// DPP row-rotate (within 16-lane rows) on the VALU pipe — no DS traffic.
template <int CTRL>
__device__ __forceinline__ float fdpp(float v) {
    int r = __builtin_amdgcn_update_dpp(
        0, __builtin_bit_cast(int, v), CTRL, 0xf, 0xf, false);
    return __builtin_bit_cast(float, r);
}

// ---------------------------------------------------------------------------
// All four weight matrices: W[256][N] fp32 -> Wt[N][256] bf16, one launch.
// ---------------------------------------------------------------------------
__global__ __launch_bounds__(256) void cvt_wall(
    const float* __restrict__ Wv, const float* __restrict__ Wo,
    const float* __restrict__ Wa, const float* __restrict__ Wu,
    short* __restrict__ Wtv, short* __restrict__ Wcat, short* __restrict__ Wtu)
{
    int idx = blockIdx.x * 256 + threadIdx.x;
    if (idx < 65536) {
        int nn = idx >> 8, k = idx & 255;
        Wtv[idx] = (short)f2bf(Wv[k * 256 + nn]);
    } else if (idx < 131072) {
        int j = idx - 65536; int nn = j >> 8, k = j & 255;
        Wcat[j] = (short)f2bf(Wo[k * 256 + nn]);
    } else if (idx < 163840) {
        int j = idx - 131072; int nn = j >> 8, k = j & 255;
        Wcat[65536 + j] = (short)f2bf(Wa[k * 128 + nn]);
    } else if (idx < 229376) {
        int j = idx - 163840; int nn = j >> 8, k = j & 255;
        Wtu[j] = (short)f2bf(Wu[k * 256 + nn]);
    }
}

// ---------------------------------------------------------------------------
// MFMA GEMM: C[M x N] = A[M x 256] * Bt[N x 256]^T + bias
// Tile 128x128, 4 waves (2x2), BK=64, K=256 fixed.
// AF32=1: A fp32, converted to bf16 during LDS staging (v_cvt_pk_bf16_f32).
// OMODE: 0 = f32 out, 1 = bf16 out, 2 = f16 out,
//        3 = split off/attn (N=384) in HEAD-MAJOR layouts,
//        4 = f16 head-major value layout (head, pixel, 32ch).
// ---------------------------------------------------------------------------
template <int AF32, int OMODE>
__global__ __launch_bounds__(256) void gemm_mfma(
    const void* __restrict__ Aptr,
    const short* __restrict__ Bt,
    const float* __restrict__ bias,
    const float* __restrict__ bias2,
    void* __restrict__ Cout,
    void* __restrict__ Cout2,
    int N)
{
    __shared__ short Al[128 * 64];
    __shared__ short Bl[128 * 64];

    const int tid  = threadIdx.x;
    const int lane = tid & 63, wid = tid >> 6;
    const int wr = wid >> 1, wc = wid & 1;
    const int bx = blockIdx.x, by = blockIdx.y;

    const long arow0 = (long)by * 128;
    const int  brow0 = bx * 128;

    const short* Abf = (const short*)Aptr;
    const float* Af  = (const float*)Aptr;

    f32x4 acc[4][4];
#pragma unroll
    for (int i = 0; i < 4; ++i)
#pragma unroll
        for (int j = 0; j < 4; ++j) acc[i][j] = (f32x4)0.f;

    bf16x8 ra[4], rb[4];
    float4 raf[4][2];

#pragma unroll
    for (int i = 0; i < 4; ++i) {
        int id = tid + i * 256, r = id >> 3, c = id & 7;
        if (AF32) {
            raf[i][0] = *(const float4*)(Af + (arow0 + r) * 256 + c * 8);
            raf[i][1] = *(const float4*)(Af + (arow0 + r) * 256 + c * 8 + 4);
        } else {
            ra[i] = *(const bf16x8*)(Abf + (arow0 + r) * 256 + c * 8);
        }
        rb[i] = *(const bf16x8*)(Bt + (long)(brow0 + r) * 256 + c * 8);
    }

    for (int step = 0; step < 4; ++step) {
#pragma unroll
        for (int i = 0; i < 4; ++i) {
            int id = tid + i * 256, r = id >> 3, c = id & 7;
            bf16x8 av;
            if (AF32) {
                unsigned q0, q1, q2, q3;
                asm("v_cvt_pk_bf16_f32 %0, %1, %2" : "=v"(q0) : "v"(raf[i][0].x), "v"(raf[i][0].y));
                asm("v_cvt_pk_bf16_f32 %0, %1, %2" : "=v"(q1) : "v"(raf[i][0].z), "v"(raf[i][0].w));
                asm("v_cvt_pk_bf16_f32 %0, %1, %2" : "=v"(q2) : "v"(raf[i][1].x), "v"(raf[i][1].y));
                asm("v_cvt_pk_bf16_f32 %0, %1, %2" : "=v"(q3) : "v"(raf[i][1].z), "v"(raf[i][1].w));
                uint4 u = make_uint4(q0, q1, q2, q3);
                av = __builtin_bit_cast(bf16x8, u);
            } else {
                av = ra[i];
            }
            *(bf16x8*)(Al + r * 64 + ((c ^ (r & 7)) * 8)) = av;
            *(bf16x8*)(Bl + r * 64 + ((c ^ (r & 7)) * 8)) = rb[i];
        }
        __syncthreads();
        if (step < 3) {
            const int k0 = (step + 1) * 64;
#pragma unroll
            for (int i = 0; i < 4; ++i) {
                int id = tid + i * 256, r = id >> 3, c = id & 7;
                if (AF32) {
                    raf[i][0] = *(const float4*)(Af + (arow0 + r) * 256 + k0 + c * 8);
                    raf[i][1] = *(const float4*)(Af + (arow0 + r) * 256 + k0 + c * 8 + 4);
                } else {
                    ra[i] = *(const bf16x8*)(Abf + (arow0 + r) * 256 + k0 + c * 8);
                }
                rb[i] = *(const bf16x8*)(Bt + (long)(brow0 + r) * 256 + k0 + c * 8);
            }
        }
#pragma unroll
        for (int kk = 0; kk < 2; ++kk) {
            const int g = lane >> 4;
            const int chunk = kk * 4 + g;
            bf16x8 af[4], bg[4];
#pragma unroll
            for (int mi = 0; mi < 4; ++mi) {
                int r = wr * 64 + mi * 16 + (lane & 15);
                af[mi] = *(const bf16x8*)(Al + r * 64 + ((chunk ^ (r & 7)) * 8));
            }
#pragma unroll
            for (int ni = 0; ni < 4; ++ni) {
                int r = wc * 64 + ni * 16 + (lane & 15);
                bg[ni] = *(const bf16x8*)(Bl + r * 64 + ((chunk ^ (r & 7)) * 8));
            }
#pragma unroll
            for (int mi = 0; mi < 4; ++mi)
#pragma unroll
                for (int ni = 0; ni < 4; ++ni)
                    acc[mi][ni] = __builtin_amdgcn_mfma_f32_16x16x32_bf16(
                        af[mi], bg[ni], acc[mi][ni], 0, 0, 0);
        }
        __syncthreads();
    }

#pragma unroll
    for (int mi = 0; mi < 4; ++mi) {
#pragma unroll
        for (int ni = 0; ni < 4; ++ni) {
            const int  col = bx * 128 + wc * 64 + ni * 16 + (lane & 15);
            const long row = (long)by * 128 + wr * 64 + mi * 16 + ((lane >> 4) * 4);
            float b;
            if (OMODE == 3) b = (col < 256) ? bias[col] : bias2[col - 256];
            else            b = bias[col];
#pragma unroll
            for (int q = 0; q < 4; ++q) {
                float v = acc[mi][ni][q] + b;
                if (OMODE == 0) {
                    ((float*)Cout)[(row + q) * N + col] = v;
                } else if (OMODE == 1) {
                    ((unsigned short*)Cout)[(row + q) * N + col] = f2bf(v);
                } else if (OMODE == 2) {
                    ((unsigned short*)Cout)[(row + q) * N + col] =
                        __builtin_bit_cast(unsigned short, (_Float16)v);
                } else if (OMODE == 4) {
                    const int mh = col >> 5, ch = col & 31;
                    ((unsigned short*)Cout)[((size_t)mh * MROWS + (row + q)) * 32 + ch] =
                        __builtin_bit_cast(unsigned short, (_Float16)v);
                } else {
                    if (col < 256) {
                        const int mh = col >> 5, ch = col & 31;
                        ((unsigned short*)Cout)[((size_t)mh * MROWS + (row + q)) * 32 + ch] = f2bf(v);
                    } else {
                        const int cc = col - 256;
                        const int mh = cc >> 4, k = cc & 15;
                        ((unsigned short*)Cout2)[((size_t)mh * MROWS + (row + q)) * 16 + k] = f2bf(v);
                    }
                }
            }
        }
    }
}

// ---------------------------------------------------------------------------
// Fused softmax + sampling; value f16 HEAD-MAJOR (head, pixel, 32ch).
// FOUR tasks per wave: producer lane = p(0..15) + 16*tq(0..3); one lane
// computes a point's BOTH y-row metas (x-pair {base, wl, wr} shared).
// DPP softmax rows = tasks. Consumer: per task 4 x dwordx4 (8 lanes x 16B
// = 128B span per meta). Measured best: 85.5us (R13 bench).
// ---------------------------------------------------------------------------
__device__ __forceinline__ void fma8(float (&a)[8], uint4 v, float w) {
    a[0] = fmaf(f16lo(v.x), w, a[0]);
    a[1] = fmaf(f16hi(v.x), w, a[1]);
    a[2] = fmaf(f16lo(v.y), w, a[2]);
    a[3] = fmaf(f16hi(v.y), w, a[3]);
    a[4] = fmaf(f16lo(v.z), w, a[4]);
    a[5] = fmaf(f16hi(v.z), w, a[5]);
    a[6] = fmaf(f16lo(v.w), w, a[6]);
    a[7] = fmaf(f16hi(v.w), w, a[7]);
}

__global__ __launch_bounds__(256, 7) void ms_sample_f16v(
    const unsigned short* __restrict__ valuef16, // (8, 43520, 32) f16 head-major
    const unsigned short* __restrict__ offbf,    // (8, 43520, 32) bf16 head-major
    const unsigned short* __restrict__ attnbf,   // (8, 43520, 16) bf16 head-major
    const float* __restrict__ refpts,            // (43520, 4, 2)
    unsigned short* __restrict__ accbf)          // (43520, 256) bf16
{
    __shared__ uint2 meta_lds[4][4][32];     // 4 KB
    __shared__ float part[4][4][32][10];     // 20 KB padded (40B stride)

    const int lane = threadIdx.x & 63;
    const int wid  = threadIdx.x >> 6;
    const int b    = blockIdx.x;
    const int m    = b / QB16;                  // head-major grid
    const int qblk = b - m * QB16;
    const int qn0w = qblk * 16 + 4 * wid;       // first qn of this wave

    // ---------------- producer: lane = p + 16*tq ----------------
    const int p   = lane & 15;
    const int tq  = lane >> 4;                  // task 0..3
    const int lvl = p >> 2;
    const int pt  = p & 3;
    const int qnl = qn0w + tq;
    const int nb  = (qnl >= LQ) ? 1 : 0;

    const size_t hq = (size_t)m * MROWS + qnl;  // head-major row index

    float lg = bf2f(attnbf[hq * 16 + p]);

    // softmax over the 16 p-lanes of this row (one row = one task)
    float mx = lg;
    mx = fmaxf(mx, fdpp<0x128>(mx));   // ror:8
    mx = fmaxf(mx, fdpp<0x124>(mx));   // ror:4
    mx = fmaxf(mx, fdpp<0x122>(mx));   // ror:2
    mx = fmaxf(mx, fdpp<0x121>(mx));   // ror:1
    float e = __expf(lg - mx);
    float s = e;
    s += fdpp<0x128>(s);
    s += fdpp<0x124>(s);
    s += fdpp<0x122>(s);
    s += fdpp<0x121>(s);
    const float aw = e * (1.0f / s);

    const int W  = 128 >> lvl;
    const int st = (lvl == 0) ? 0 : (lvl == 1) ? 16384
                 : (lvl == 2) ? 20480 : 21504;
    const float fW = (float)W;

    const float2 rxy = *(const float2*)&refpts[(size_t)qnl * 8 + lvl * 2];
    unsigned oo = *(const unsigned*)(offbf + hq * 32 + lvl * 8 + pt * 2);
    const float ox = bf2f((unsigned short)(oo & 0xffff));
    const float oy = bf2f((unsigned short)(oo >> 16));

    const float x = fmaf(rxy.x, fW, ox) - 0.5f;
    const float y = fmaf(rxy.y, fW, oy) - 0.5f;
    const float x0f = floorf(x), y0f = floorf(y);
    const float fx = x - x0f, fy = y - y0f;
    const int x0i = (int)x0f;
    const int y0i = (int)y0f;

    // y-row weights (both rows in one lane)
    const bool y0ok = (y0i >= 0) & (y0i <= W - 1);
    const bool y1ok = (y0i + 1 >= 0) & (y0i + 1 <= W - 1);
    const float awwy0 = y0ok ? aw * (1.0f - fy) : 0.0f;
    const float awwy1 = y1ok ? aw * fy : 0.0f;
    const int yc0 = min(max(y0i, 0), W - 1);
    const int yc1 = min(max(y0i + 1, 0), W - 1);

    // x-pair (shared across both y-rows)
    const bool x0ok = (x0i >= 0) & (x0i <= W - 1);
    const bool x1ok = (x0i + 1 >= 0) & (x0i + 1 <= W - 1);
    const float wx0 = x0ok ? (1.0f - fx) : 0.0f;
    const float wx1 = x1ok ? fx : 0.0f;
    const int bxp = min(max(x0i, 0), W - 2);
    const bool bis = (x0i == bxp);
    const float wxl = bis ? wx0 : wx1;
    const float wxr = bis ? wx1 : wx0;

    const int base0 = nb * 21760 + st + bxp;
    const int addr0 = base0 + yc0 * W;
    const int addr1 = base0 + yc1 * W;

    const unsigned wp0 =
        (unsigned)__builtin_bit_cast(unsigned short, (_Float16)(awwy0 * wxl)) |
        ((unsigned)__builtin_bit_cast(unsigned short, (_Float16)(awwy0 * wxr)) << 16);
    const unsigned wp1 =
        (unsigned)__builtin_bit_cast(unsigned short, (_Float16)(awwy1 * wxl)) |
        ((unsigned)__builtin_bit_cast(unsigned short, (_Float16)(awwy1 * wxr)) << 16);

    meta_lds[wid][tq][p * 2 + 0] = make_uint2((unsigned)addr0, wp0);
    meta_lds[wid][tq][p * 2 + 1] = make_uint2((unsigned)addr1, wp1);

    asm volatile("s_waitcnt lgkmcnt(0)" ::: "memory");
    __builtin_amdgcn_sched_barrier(0);

    // ---------------- consumer: lane = cg + 8*slot ----------------
    const int cg   = lane & 7;
    const int slot = lane >> 3;
    const char* vbh = (const char*)(valuef16 + (size_t)m * MROWS * 32);
    const unsigned mc = (unsigned)(cg * 16);
    const int wsh = (cg >> 2) << 4;     // 0: L-pixel weight, 16: R-pixel

    float a0[8] = {}, a1[8] = {}, a2[8] = {}, a3[8] = {};

    auto do_task = [&](int t, float (&a)[8]) {
        uint2 mt[4];
#pragma unroll
        for (int it = 0; it < 4; ++it)
            mt[it] = meta_lds[wid][t][it * 8 + slot];
        uint4 vv[4];
#pragma unroll
        for (int it = 0; it < 4; ++it)
            vv[it] = *(const uint4*)(vbh + (((size_t)mt[it].x) << 6) + mc);
#pragma unroll
        for (int it = 0; it < 4; ++it) {
            const float w = (float)__builtin_bit_cast(
                _Float16, (unsigned short)((mt[it].y >> wsh) & 0xffffu));
            fma8(a, vv[it], w);
        }
    };
    do_task(0, a0);
    do_task(1, a1);
    do_task(2, a2);
    do_task(3, a3);

    // fold slot parity (lane^8 within 16-row) on the VALU pipe
#pragma unroll
    for (int jj = 0; jj < 8; ++jj) {
        a0[jj] += fdpp<0x128>(a0[jj]);
        a1[jj] += fdpp<0x128>(a1[jj]);
        a2[jj] += fdpp<0x128>(a2[jj]);
        a3[jj] += fdpp<0x128>(a3[jj]);
    }

    // even-slot lanes write partials: idx = grp(lane>>4)*8 + cg, 40B stride
    if ((lane & 8) == 0) {
        const int idx = (lane >> 4) * 8 + cg;
        float* pp0 = &part[wid][0][idx][0];
        float* pp1 = &part[wid][1][idx][0];
        float* pp2 = &part[wid][2][idx][0];
        float* pp3 = &part[wid][3][idx][0];
        *(float2*)&pp0[0] = make_float2(a0[0], a0[1]);
        *(float2*)&pp0[2] = make_float2(a0[2], a0[3]);
        *(float2*)&pp0[4] = make_float2(a0[4], a0[5]);
        *(float2*)&pp0[6] = make_float2(a0[6], a0[7]);
        *(float2*)&pp1[0] = make_float2(a1[0], a1[1]);
        *(float2*)&pp1[2] = make_float2(a1[2], a1[3]);
        *(float2*)&pp1[4] = make_float2(a1[4], a1[5]);
        *(float2*)&pp1[6] = make_float2(a1[6], a1[7]);
        *(float2*)&pp2[0] = make_float2(a2[0], a2[1]);
        *(float2*)&pp2[2] = make_float2(a2[2], a2[3]);
        *(float2*)&pp2[4] = make_float2(a2[4], a2[5]);
        *(float2*)&pp2[6] = make_float2(a2[6], a2[7]);
        *(float2*)&pp3[0] = make_float2(a3[0], a3[1]);
        *(float2*)&pp3[2] = make_float2(a3[2], a3[3]);
        *(float2*)&pp3[4] = make_float2(a3[4], a3[5]);
        *(float2*)&pp3[6] = make_float2(a3[6], a3[7]);
    }
    asm volatile("s_waitcnt lgkmcnt(0)" ::: "memory");
    __builtin_amdgcn_sched_barrier(0);

    // 64 lanes write all 4 tasks: lanes 0-31 -> tasks {0,1}, 32-63 -> {2,3}
#pragma unroll
    for (int tt = 0; tt < 2; ++tt) {
        const int t  = (lane >> 5) * 2 + tt;
        const int ch = lane & 31;
        const int o  = ch >> 3, k = ch & 7;
        float sum = 0.f;
#pragma unroll
        for (int grp = 0; grp < 4; ++grp)
            sum += part[wid][t][grp * 8 + o][k] + part[wid][t][grp * 8 + o + 4][k];
        accbf[(size_t)(qn0w + t) * 256 + m * 32 + ch] = f2bf(sum);
    }
}

// ---------------------------------------------------------------------------
// fp32 fallback kernels (used only if workspace is too small)
// ---------------------------------------------------------------------------
__global__ __launch_bounds__(256) void gemm_k256(
    const float* __restrict__ A, const float* __restrict__ B,
    const float* __restrict__ bias, float* __restrict__ C,
    int M, int N)
{
    __shared__ float As[16][68];
    __shared__ float Bs[16][68];

    const int tid = threadIdx.x;
    const int tx = tid & 15, ty = tid >> 4;
    const int bx = blockIdx.x, by = blockIdx.y;

    const int arow = tid >> 2;
    const int ak   = (tid & 3) << 2;
    const int bk   = tid >> 4;
    const int bcol = (tid & 15) << 2;

    const float* Ag = A + (long)(by * 64 + arow) * 256 + ak;
    const float* Bg = B + (long)bk * N + bx * 64 + bcol;

    float acc[4][4] = {};

    for (int k0 = 0; k0 < 256; k0 += 16) {
        float4 av = *(const float4*)(Ag + k0);
        float4 bv = *(const float4*)(Bg + (long)k0 * N);
        As[ak + 0][arow] = av.x;
        As[ak + 1][arow] = av.y;
        As[ak + 2][arow] = av.z;
        As[ak + 3][arow] = av.w;
        *(float4*)&Bs[bk][bcol] = bv;
        __syncthreads();
#pragma unroll
        for (int k = 0; k < 16; ++k) {
            float4 a4 = *(const float4*)&As[k][ty * 4];
            float4 b4 = *(const float4*)&Bs[k][tx * 4];
            float a[4] = {a4.x, a4.y, a4.z, a4.w};
            float bb[4] = {b4.x, b4.y, b4.z, b4.w};
#pragma unroll
            for (int i = 0; i < 4; ++i)
#pragma unroll
                for (int j = 0; j < 4; ++j)
                    acc[i][j] = fmaf(a[i], bb[j], acc[i][j]);
        }
        __syncthreads();
    }

    float4 b4 = *(const float4*)&bias[bx * 64 + tx * 4];
#pragma unroll
    for (int i = 0; i < 4; ++i) {
        float4 o;
        o.x = acc[i][0] + b4.x;
        o.y = acc[i][1] + b4.y;
        o.z = acc[i][2] + b4.z;
        o.w = acc[i][3] + b4.w;
        *(float4*)&C[(long)(by * 64 + ty * 4 + i) * N + bx * 64 + tx * 4] = o;
    }
}

__global__ __launch_bounds__(256) void ms_sample_f32(
    const float* __restrict__ value,
    const float* __restrict__ offraw,
    const float* __restrict__ attnraw,
    const float* __restrict__ refpts,
    float* __restrict__ acc_out)
{
    const int lane = threadIdx.x & 63;
    const int wid  = threadIdx.x >> 6;
    const long t   = (long)blockIdx.x * 4 + wid;

    const int  m  = (int)(t & 7);
    const long qn = t >> 3;

    const int p   = lane >> 2;
    const int c   = lane & 3;
    const int cx  = c & 1, cy = c >> 1;
    const int lvl = p >> 2;
    const int pt  = p & 3;

    float lg = attnraw[qn * 128 + m * 16 + p];
    float mx = lg;
    mx = fmaxf(mx, __shfl_xor(mx, 4));
    mx = fmaxf(mx, __shfl_xor(mx, 8));
    mx = fmaxf(mx, __shfl_xor(mx, 16));
    mx = fmaxf(mx, __shfl_xor(mx, 32));
    float e = __expf(lg - mx);
    float s = e;
    s += __shfl_xor(s, 4);
    s += __shfl_xor(s, 8);
    s += __shfl_xor(s, 16);
    s += __shfl_xor(s, 32);
    const float aw = e * (1.0f / s);

    const int W  = 128 >> lvl;
    const int st = (lvl == 0) ? 0 : (lvl == 1) ? 16384
                 : (lvl == 2) ? 20480 : 21504;
    const float fW = (float)W;

    const float2 rxy = *(const float2*)&refpts[qn * 8 + lvl * 2];
    float2 o2 = *(const float2*)(offraw + qn * 256 + m * 32 + lvl * 8 + pt * 2);

    const float x = fmaf(rxy.x, fW, o2.x) - 0.5f;
    const float y = fmaf(rxy.y, fW, o2.y) - 0.5f;
    const float x0f = floorf(x), y0f = floorf(y);
    const float fx = x - x0f, fy = y - y0f;
    const int xi = (int)x0f + cx;
    const int yi = (int)y0f + cy;
    const float wx = cx ? fx : (1.0f - fx);
    const float wy = cy ? fy : (1.0f - fy);
    const bool ok = (xi >= 0) & (xi <= W - 1) & (yi >= 0) & (yi <= W - 1);
    const float wt = ok ? aw * wx * wy : 0.0f;
    const int xc = min(max(xi, 0), W - 1);
    const int yc = min(max(yi, 0), W - 1);
    const int addr = st + yc * W + xc;

    const int cg   = lane & 7;
    const int slot = lane >> 3;

    const long nn = qn / LQ;
    const float4* v4 = (const float4*)(value + (nn * (long)LQ) * 256 + m * 32);

    float4 acc = make_float4(0.f, 0.f, 0.f, 0.f);
#pragma unroll
    for (int it = 0; it < 8; ++it) {
        const int src = 8 * it + slot;
        const int   a = __shfl(addr, src);
        const float w = __shfl(wt, src);
        const float4 v = v4[(long)a * 64 + cg];
        acc.x = fmaf(w, v.x, acc.x);
        acc.y = fmaf(w, v.y, acc.y);
        acc.z = fmaf(w, v.z, acc.z);
        acc.w = fmaf(w, v.w, acc.w);
    }

#pragma unroll
    for (int mask = 8; mask <= 32; mask <<= 1) {
        acc.x += __shfl_xor(acc.x, mask);
        acc.y += __shfl_xor(acc.y, mask);
        acc.z += __shfl_xor(acc.z, mask);
        acc.w += __shfl_xor(acc.w, mask);
    }

    if (lane < 8)
        *(float4*)(acc_out + qn * 256 + m * 32 + cg * 4) = acc;
}

__global__ __launch_bounds__(256) void outproj_inplace(
    float* __restrict__ io, const float* __restrict__ W,
    const float* __restrict__ bias)
{
    __shared__ float As[32][260];
    __shared__ float Bs[16][260];

    const int tid = threadIdx.x;
    const long rbase = (long)blockIdx.x * 32;

#pragma unroll
    for (int i = 0; i < 8; ++i) {
        int f4 = i * 256 + tid;
        int r  = f4 >> 6;
        int c4 = (f4 & 63) << 2;
        float4 v = *(const float4*)&io[(rbase + r) * 256 + c4];
        *(float4*)&As[r][c4] = v;
    }
    __syncthreads();

    const int tx = tid & 15, ty = tid >> 4;
    float acc[2][16] = {};

    for (int k0 = 0; k0 < 256; k0 += 16) {
#pragma unroll
        for (int i = 0; i < 4; ++i) {
            int f4 = i * 256 + tid;
            int kr = f4 >> 6;
            int c4 = (f4 & 63) << 2;
            float4 v = *(const float4*)&W[(long)(k0 + kr) * 256 + c4];
            *(float4*)&Bs[kr][c4] = v;
        }
        __syncthreads();
#pragma unroll
        for (int k = 0; k < 16; ++k) {
            float a0 = As[ty * 2 + 0][k0 + k];
            float a1 = As[ty * 2 + 1][k0 + k];
#pragma unroll
            for (int jj = 0; jj < 4; ++jj) {
                float4 b = *(const float4*)&Bs[k][tx * 4 + jj * 64];
                acc[0][jj * 4 + 0] = fmaf(a0, b.x, acc[0][jj * 4 + 0]);
                acc[0][jj * 4 + 1] = fmaf(a0, b.y, acc[0][jj * 4 + 1]);
                acc[0][jj * 4 + 2] = fmaf(a0, b.z, acc[0][jj * 4 + 2]);
                acc[0][jj * 4 + 3] = fmaf(a0, b.w, acc[0][jj * 4 + 3]);
                acc[1][jj * 4 + 0] = fmaf(a1, b.x, acc[1][jj * 4 + 0]);
                acc[1][jj * 4 + 1] = fmaf(a1, b.y, acc[1][jj * 4 + 1]);
                acc[1][jj * 4 + 2] = fmaf(a1, b.z, acc[1][jj * 4 + 2]);
                acc[1][jj * 4 + 3] = fmaf(a1, b.w, acc[1][jj * 4 + 3]);
            }
        }
        __syncthreads();
    }

#pragma unroll
    for (int i = 0; i < 2; ++i)
#pragma unroll
        for (int jj = 0; jj < 4; ++jj) {
            float4 b = *(const float4*)&bias[tx * 4 + jj * 64];
            float4 o;
            o.x = acc[i][jj * 4 + 0] + b.x;
            o.y = acc[i][jj * 4 + 1] + b.y;
            o.z = acc[i][jj * 4 + 2] + b.z;
            o.w = acc[i][jj * 4 + 3] + b.w;
            *(float4*)&io[(rbase + ty * 2 + i) * 256 + tx * 4 + jj * 64] = o;
        }
}

// ---------------------------------------------------------------------------
extern "C" void kernel_launch(void* const* d_in, const int* in_sizes, int n_in,
                              void* d_out, int out_size, void* d_ws, size_t ws_size,
                              hipStream_t stream)
{
    const float* query         = (const float*)d_in[0];
    const float* refpts        = (const float*)d_in[1];
    const float* input_flatten = (const float*)d_in[2];
    const float* W_off         = (const float*)d_in[3];
    const float* b_off         = (const float*)d_in[4];
    const float* W_attn        = (const float*)d_in[5];
    const float* b_attn        = (const float*)d_in[6];
    const float* W_val         = (const float*)d_in[7];
    const float* b_val         = (const float*)d_in[8];
    const float* W_out         = (const float*)d_in[9];
    const float* b_out         = (const float*)d_in[10];
    float* out = (float*)d_out;

    dim3 blk(256);

    const size_t NEED_BF = 78446592ULL;
    if (ws_size >= NEED_BF) {
        // -------- bf16/f16 MFMA path --------
        char* w = (char*)d_ws;
        unsigned short* valuef16 = (unsigned short*)w;               // 22,282,240
        unsigned short* offbf    = (unsigned short*)(w + 22282240);  // 22,282,240
        unsigned short* attnbf   = (unsigned short*)(w + 44564480);  // 11,141,120
        unsigned short* accbf    = (unsigned short*)(w + 55705600);  // 22,282,240
        short*          Wtv      = (short*)(w + 77987840);           // 131,072
        short*          Wcat     = (short*)(w + 78118912);           // 196,608
        short*          Wtu      = (short*)(w + 78315520);           // 131,072

        cvt_wall<<<dim3(896), blk, 0, stream>>>(
            W_val, W_off, W_attn, W_out, Wtv, Wcat, Wtu);

        // value in f16 head-major (head, pixel, 32ch)
        gemm_mfma<1, 4><<<dim3(2, MROWS / 128), blk, 0, stream>>>(
            input_flatten, Wtv, b_val, nullptr, valuef16, nullptr, 256);
        // off/attn in head-major layouts
        gemm_mfma<1, 3><<<dim3(3, MROWS / 128), blk, 0, stream>>>(
            query, Wcat, b_off, b_attn, offbf, attnbf, 384);

        // head-major grid, 16 tasks/block (4 tasks per wave)
        ms_sample_f16v<<<dim3(QB16 * 8), blk, 0, stream>>>(
            valuef16, offbf, attnbf, refpts, accbf);

        gemm_mfma<0, 0><<<dim3(2, MROWS / 128), blk, 0, stream>>>(
            accbf, Wtu, b_out, nullptr, out, nullptr, 256);
    } else {
        // -------- fp32 fallback path --------
        float* ws = (float*)d_ws;
        float* value   = ws;
        float* offraw  = value  + (long)MROWS * 256;
        float* attnraw = offraw + (long)MROWS * 256;
        float* accbuf  = attnraw + (long)MROWS * 128;

        const size_t need_with_acc =
            ((size_t)MROWS * 256 * 3 + (size_t)MROWS * 128) * sizeof(float);
        const bool has_acc = ws_size >= need_with_acc;

        gemm_k256<<<dim3(4, MROWS / 64), blk, 0, stream>>>(input_flatten, W_val, b_val, value, MROWS, 256);
        gemm_k256<<<dim3(4, MROWS / 64), blk, 0, stream>>>(query, W_off, b_off, offraw, MROWS, 256);
        gemm_k256<<<dim3(2, MROWS / 64), blk, 0, stream>>>(query, W_attn, b_attn, attnraw, MROWS, 128);

        float* accp = has_acc ? accbuf : out;
        ms_sample_f32<<<dim3((NBATCH * LQ * 8) / 4), blk, 0, stream>>>(
            value, offraw, attnraw, refpts, accp);

        if (has_acc)
            gemm_k256<<<dim3(4, MROWS / 64), blk, 0, stream>>>(accbuf, W_out, b_out, out, MROWS, 256);
        else
            outproj_inplace<<<dim3(MROWS / 32), blk, 0, stream>>>(out, W_out, b_out);
    }
}